// Round 15
// baseline (345.204 us; speedup 1.0000x reference)
//
#include <hip/hip_runtime.h>
#include <hip/hip_fp16.h>

#define IN_F   2048
#define OUT_F  2048
#define NNZ_   1048576
#define BATCH  8192
#define W_ROW0 6144
#define W_BASE ((size_t)W_ROW0 * OUT_F)   // W fp32 parked at out rows [6144,8192)

typedef __bf16 bf16x8 __attribute__((ext_vector_type(8)));
typedef float  f32x4  __attribute__((ext_vector_type(4)));

__device__ __forceinline__ float bfval(unsigned short b) {
    union { unsigned int u; float f; } t; t.u = ((unsigned int)b) << 16; return t.f;
}
__device__ __forceinline__ unsigned short f2bf(float f) {
    union { float f; unsigned int u; } v; v.f = f;
    unsigned int u = v.u; u += 0x7FFF + ((u >> 16) & 1);   // RNE
    return (unsigned short)(u >> 16);
}
__device__ __forceinline__ float h2f(unsigned short b) {
    union { unsigned short u; __half h; } t; t.u = b; return __half2float(t.h);
}
__device__ __forceinline__ void gload_lds16(const void* g, void* l) {
    __builtin_amdgcn_global_load_lds(
        (const __attribute__((address_space(1))) unsigned int*)g,
        (__attribute__((address_space(3))) unsigned int*)l,
        16, 0, 0);
}

// ---- zero W region ----
__global__ void zero_f32_kernel(float4* __restrict__ p, int n4) {
    int s = gridDim.x * blockDim.x;
    for (int i = blockIdx.x * blockDim.x + threadIdx.x; i < n4; i += s)
        p[i] = float4{0.f, 0.f, 0.f, 0.f};
}

// ---- scatter COO -> dense W, 3-way dtype detection (r9-proven verbatim) ----
__global__ void scatter_w_kernel(const unsigned short* __restrict__ wbits,
                                 const int* __restrict__ coords,
                                 float* __restrict__ W, int nnz) {
    __shared__ unsigned int sbf, sfh;
    if (threadIdx.x == 0) { sbf = 0u; sfh = 0u; }
    __syncthreads();
    unsigned int mbf = 0u, mfh = 0u;
    for (int i = threadIdx.x; i < 512; i += blockDim.x) {
        unsigned short b = wbits[i];
        unsigned int abf = (((unsigned int)b) << 16) & 0x7FFFFFFFu;
        unsigned int afh = (unsigned int)(b & 0x7FFF);
        mbf = mbf > abf ? mbf : abf;
        mfh = mfh > afh ? mfh : afh;
    }
    atomicMax(&sbf, mbf); atomicMax(&sfh, mfh);
    __syncthreads();
    union { unsigned int u; float f; } tb; tb.u = sbf;
    float bmax = tb.f;
    float hmax = h2f((unsigned short)sfh);
    int mode = (bmax > 1e-3f && bmax < 16.f) ? 0
             : (hmax > 1e-3f && hmax < 16.f) ? 1 : 2;   // resolved on HW: 2 (fp32)

    int i = blockIdx.x * blockDim.x + threadIdx.x;
    if (i < nnz) {
        float v;
        if (mode == 0)      v = bfval(wbits[i]);
        else if (mode == 1) v = h2f(wbits[i]);
        else                v = ((const float*)wbits)[i];
        atomicAdd(&W[coords[i] & (OUT_F * IN_F - 1)], v);
    }
}

// ---- W fp32 -> wb bf16 ----
__global__ void f32_to_bf16_kernel(const float4* __restrict__ in,
                                   ushort4* __restrict__ out, int n4) {
    int s = gridDim.x * blockDim.x;
    for (int i = blockIdx.x * blockDim.x + threadIdx.x; i < n4; i += s) {
        float4 v = in[i];
        ushort4 o;
        o.x = f2bf(v.x); o.y = f2bf(v.y); o.z = f2bf(v.z); o.w = f2bf(v.w);
        out[i] = o;
    }
}

// ---- 256x256 GEMM: A = fp32 x reg-staged+cvt (T14), B = bf16 gload_lds ----
// 16 waves (4x4), 64x64/wave, counted vmcnt, T2 swizzle. LDS layout rule:
// LDS[row][slot s] = src[row][s ^ (row&7)]  (16B slots; readers use s0^ks*4).
__global__ __launch_bounds__(1024, 4) void gemm256_kernel(
    const float* __restrict__ xf,             // [8192][2048] fp32
    const unsigned short* __restrict__ wb,    // [2048][2048] bf16 bits
    float* __restrict__ out) {
    constexpr int K = IN_F;
    constexpr int NT = K / 64;                 // 32 K-tiles

    __shared__ __align__(16) unsigned short As[2][256 * 64];   // 64 KiB
    __shared__ __align__(16) unsigned short Bs[2][256 * 64];   // 64 KiB

    const int tid  = threadIdx.x;
    const int lane = tid & 63;
    const int wave = tid >> 6;        // 0..15
    const int wr   = wave >> 2;       // M quarter
    const int wc   = wave & 3;        // N quarter
    const int frow = lane & 15;
    const int klan = lane >> 4;
    const int s0   = klan ^ (lane & 7);

    const int flat = blockIdx.x;
    const int swz  = (flat & 7) * 32 + (flat >> 3);   // XCD swizzle
    const int tm   = swz & 31;
    const int tn   = swz >> 5;

    const unsigned short* srcB = wb + (size_t)tn * 256 * K;

    // B staging (gload_lds, linear dest + pre-swizzled source) — r14 verbatim
    const int rloc  = lane >> 3;
    const int sslot = (lane & 7) ^ rloc;

    // A staging (reg): lane -> row wave*16 + (lane>>2); source slots as0, as0+4
    const int arl  = lane >> 2;                 // 0..15
    const int as0  = lane & 3;                  // 0..3
    const float* srcAx = xf + (size_t)(tm * 256 + wave * 16 + arl) * K;

    f32x4 acc[4][4] = {};

    auto stageB = [&](int buf, int kt) {
        const size_t coff = (size_t)kt * 64 + sslot * 8;
#pragma unroll
        for (int c = 0; c < 2; ++c) {
            const int row = c * 128 + wave * 8;  // wave-uniform
            gload_lds16(srcB + (size_t)(row + rloc) * K + coff,
                        &Bs[buf][row * 64]);
        }
    };
    auto aload = [&](int kt, float4 (&v)[4]) {
        const float* p = srcAx + kt * 64;
        v[0] = *(const float4*)(p + as0 * 8);
        v[1] = *(const float4*)(p + as0 * 8 + 4);
        v[2] = *(const float4*)(p + (as0 + 4) * 8);
        v[3] = *(const float4*)(p + (as0 + 4) * 8 + 4);
    };
    auto awrite = [&](int buf, float4 (&v)[4]) {
        bf16x8 t0, t1;
        t0[0] = (__bf16)v[0].x; t0[1] = (__bf16)v[0].y;
        t0[2] = (__bf16)v[0].z; t0[3] = (__bf16)v[0].w;
        t0[4] = (__bf16)v[1].x; t0[5] = (__bf16)v[1].y;
        t0[6] = (__bf16)v[1].z; t0[7] = (__bf16)v[1].w;
        t1[0] = (__bf16)v[2].x; t1[1] = (__bf16)v[2].y;
        t1[2] = (__bf16)v[2].z; t1[3] = (__bf16)v[2].w;
        t1[4] = (__bf16)v[3].x; t1[5] = (__bf16)v[3].y;
        t1[6] = (__bf16)v[3].z; t1[7] = (__bf16)v[3].w;
        const int r  = wave * 16 + arl;
        const int s1 = as0 ^ (arl & 7);
        const int s2 = (as0 + 4) ^ (arl & 7);
        *(bf16x8*)&As[buf][r * 64 + s1 * 8] = t0;
        *(bf16x8*)&As[buf][r * 64 + s2 * 8] = t1;
    };
    auto compute = [&](int buf) {
#pragma unroll
        for (int ks = 0; ks < 2; ++ks) {
            const int sl = s0 ^ (ks * 4);
            bf16x8 af[4], bg[4];
#pragma unroll
            for (int mf = 0; mf < 4; ++mf)
                af[mf] = *(const bf16x8*)
                    &As[buf][(wr * 64 + mf * 16 + frow) * 64 + sl * 8];
#pragma unroll
            for (int nf = 0; nf < 4; ++nf)
                bg[nf] = *(const bf16x8*)
                    &Bs[buf][(wc * 64 + nf * 16 + frow) * 64 + sl * 8];
            __builtin_amdgcn_s_setprio(1);
#pragma unroll
            for (int mf = 0; mf < 4; ++mf)
#pragma unroll
                for (int nf = 0; nf < 4; ++nf)
                    acc[mf][nf] = __builtin_amdgcn_mfma_f32_16x16x32_bf16(
                        af[mf], bg[nf], acc[mf][nf], 0, 0, 0);
            __builtin_amdgcn_s_setprio(0);
        }
    };

    float4 r0[4], r1[4];
    // prologue: queue = B0(2), A0(4), B1(2), A1(4) = 12 outstanding
    stageB(0, 0);
    aload(0, r0);
    stageB(1, 1);
    aload(1, r1);
    asm volatile("s_waitcnt vmcnt(6)" ::: "memory");   // B0 + A0 landed
    awrite(0, r0);

    // iter body: named reg sets (rule #20); steady-state vmcnt(2)
    auto iter = [&](int kt, float4 (&rfree)[4], float4 (&rnext)[4]) {
        const int buf = kt & 1;
        asm volatile("s_waitcnt lgkmcnt(0)" ::: "memory");  // my A-writes done
        __builtin_amdgcn_s_barrier();                       // all writes visible
        compute(buf);
        asm volatile("" ::: "memory");
        __builtin_amdgcn_s_barrier();                       // all reads of buf done
        if (kt + 2 < NT) stageB(buf, kt + 2);
        if (kt + 1 < NT) {
            if (kt + 2 < NT) asm volatile("s_waitcnt vmcnt(2)" ::: "memory");
            else             asm volatile("s_waitcnt vmcnt(0)" ::: "memory");
            awrite(buf ^ 1, rnext);                         // A(kt+1) -> LDS
            if (kt + 2 < NT) aload(kt + 2, rfree);          // prefetch A(kt+2)
        }
    };
    for (int kt = 0; kt < NT; kt += 2) {
        iter(kt, r0, r1);
        iter(kt + 1, r1, r0);
    }

    // epilogue: C/D layout col=lane&15, row=(lane>>4)*4+reg  [validated]
    const int orow0 = tm * 256 + wr * 64 + klan * 4;
    const int ocol0 = tn * 256 + wc * 64 + frow;
#pragma unroll
    for (int mf = 0; mf < 4; ++mf)
#pragma unroll
        for (int nf = 0; nf < 4; ++nf)
#pragma unroll
            for (int r = 0; r < 4; ++r)
                out[(size_t)(orow0 + mf * 16 + r) * OUT_F + ocol0 + nf * 16]
                    = acc[mf][nf][r];
}

extern "C" void kernel_launch(void* const* d_in, const int* in_sizes, int n_in,
                              void* d_out, int out_size, void* d_ws, size_t ws_size,
                              hipStream_t stream) {
    const float*          x      = (const float*)d_in[0];
    const unsigned short* wbits  = (const unsigned short*)d_in[1];  // fp32-delivered
    const int*            coords = (const int*)d_in[2];             // int32
    float*                out    = (float*)d_out;                   // fp32

    float*          W  = out + W_BASE;           // 16 MiB, dies before GEMM writes
    unsigned short* wb = (unsigned short*)d_ws;  // 8 MiB (ws >= 9 MiB proven)
    (void)ws_size; (void)in_sizes; (void)n_in; (void)out_size;

    zero_f32_kernel<<<512, 256, 0, stream>>>((float4*)W, OUT_F * IN_F / 4);
    scatter_w_kernel<<<NNZ_ / 256, 256, 0, stream>>>(wbits, coords, W, NNZ_);
    f32_to_bf16_kernel<<<1024, 256, 0, stream>>>(
        (const float4*)W, (ushort4*)wb, OUT_F * IN_F / 4);

    gemm256_kernel<<<256, 1024, 0, stream>>>(x, wb, out);
}

// Round 16
// 147.389 us; speedup vs baseline: 2.3421x; 2.3421x over previous
//
#include <hip/hip_runtime.h>
#include <hip/hip_fp16.h>

#define IN_F   2048
#define OUT_F  2048
#define NNZ_   1048576
#define BATCH  8192
#define W_ROW0 6144
#define W_BASE ((size_t)W_ROW0 * OUT_F)   // W fp32 parked at out rows [6144,8192)

typedef __bf16 bf16x8 __attribute__((ext_vector_type(8)));
typedef float  f32x4  __attribute__((ext_vector_type(4)));

__device__ __forceinline__ float bfval(unsigned short b) {
    union { unsigned int u; float f; } t; t.u = ((unsigned int)b) << 16; return t.f;
}
__device__ __forceinline__ unsigned short f2bf(float f) {
    union { float f; unsigned int u; } v; v.f = f;
    unsigned int u = v.u; u += 0x7FFF + ((u >> 16) & 1);   // RNE
    return (unsigned short)(u >> 16);
}
__device__ __forceinline__ float h2f(unsigned short b) {
    union { unsigned short u; __half h; } t; t.u = b; return __half2float(t.h);
}
__device__ __forceinline__ void gload_lds16(const void* g, void* l) {
    __builtin_amdgcn_global_load_lds(
        (const __attribute__((address_space(1))) unsigned int*)g,
        (__attribute__((address_space(3))) unsigned int*)l,
        16, 0, 0);
}

// ---- zero W region (must globally precede scatter atomics) ----
__global__ void zero_f32_kernel(float4* __restrict__ p, int n4) {
    int s = gridDim.x * blockDim.x;
    for (int i = blockIdx.x * blockDim.x + threadIdx.x; i < n4; i += s)
        p[i] = float4{0.f, 0.f, 0.f, 0.f};
}

// ---- fused: blocks [0,4096) scatter COO->W; blocks [4096,6144) x->bf16 ----
// The two halves are data-independent; fusing runs them CONCURRENTLY on
// different CUs instead of serially on the stream (saves ~20 us + one gap).
__global__ void scatter_xcvt_kernel(const unsigned short* __restrict__ wbits,
                                    const int* __restrict__ coords,
                                    float* __restrict__ W,
                                    const float4* __restrict__ x,
                                    ushort4* __restrict__ xb) {
    if (blockIdx.x < 4096) {
        // ---- scatter with 3-way weights-dtype detection (r9-proven) ----
        __shared__ unsigned int sbf, sfh;
        if (threadIdx.x == 0) { sbf = 0u; sfh = 0u; }
        __syncthreads();
        unsigned int mbf = 0u, mfh = 0u;
        for (int i = threadIdx.x; i < 512; i += blockDim.x) {
            unsigned short b = wbits[i];
            unsigned int abf = (((unsigned int)b) << 16) & 0x7FFFFFFFu;
            unsigned int afh = (unsigned int)(b & 0x7FFF);
            mbf = mbf > abf ? mbf : abf;
            mfh = mfh > afh ? mfh : afh;
        }
        atomicMax(&sbf, mbf); atomicMax(&sfh, mfh);
        __syncthreads();
        union { unsigned int u; float f; } tb; tb.u = sbf;
        float bmax = tb.f;
        float hmax = h2f((unsigned short)sfh);
        int mode = (bmax > 1e-3f && bmax < 16.f) ? 0
                 : (hmax > 1e-3f && hmax < 16.f) ? 1 : 2;  // on HW: 2 (fp32)

        int i = blockIdx.x * blockDim.x + threadIdx.x;
        if (i < NNZ_) {
            float v;
            if (mode == 0)      v = bfval(wbits[i]);
            else if (mode == 1) v = h2f(wbits[i]);
            else                v = ((const float*)wbits)[i];
            atomicAdd(&W[coords[i] & (OUT_F * IN_F - 1)], v);
        }
    } else {
        // ---- x fp32 -> xb bf16, grid-stride over 2048 blocks ----
        const int t0     = (blockIdx.x - 4096) * blockDim.x + threadIdx.x;
        const int stride = 2048 * blockDim.x;
        for (int i = t0; i < BATCH * IN_F / 4; i += stride) {
            float4 v = x[i];
            ushort4 o;
            o.x = f2bf(v.x); o.y = f2bf(v.y); o.z = f2bf(v.z); o.w = f2bf(v.w);
            xb[i] = o;
        }
    }
}

// ---- W fp32 -> wb bf16 ----
__global__ void f32_to_bf16_kernel(const float4* __restrict__ in,
                                   ushort4* __restrict__ out, int n4) {
    int s = gridDim.x * blockDim.x;
    for (int i = blockIdx.x * blockDim.x + threadIdx.x; i < n4; i += s) {
        float4 v = in[i];
        ushort4 o;
        o.x = f2bf(v.x); o.y = f2bf(v.y); o.z = f2bf(v.z); o.w = f2bf(v.w);
        out[i] = o;
    }
}

// ---- 256x256 bf16 GEMM (r14 VERBATIM: 16 waves 4x4, 64x64/wave, counted
//      vmcnt, T2 swizzle via pre-swizzled gload_lds source, XCD swizzle) ----
__global__ __launch_bounds__(1024, 4) void gemm256_kernel(
    const unsigned short* __restrict__ xb,
    const unsigned short* __restrict__ wb,
    float* __restrict__ out) {
    constexpr int K = IN_F;
    constexpr int NT = K / 64;                 // 32 K-tiles

    __shared__ __align__(16) unsigned short As[2][256 * 64];   // 64 KiB
    __shared__ __align__(16) unsigned short Bs[2][256 * 64];   // 64 KiB

    const int tid  = threadIdx.x;
    const int lane = tid & 63;
    const int wave = tid >> 6;        // 0..15
    const int wr   = wave >> 2;       // M quarter
    const int wc   = wave & 3;        // N quarter
    const int frow = lane & 15;
    const int klan = lane >> 4;
    const int s0   = klan ^ (lane & 7);

    const int flat = blockIdx.x;
    const int swz  = (flat & 7) * 32 + (flat >> 3);   // XCD swizzle
    const int tm   = swz & 31;
    const int tn   = swz >> 5;

    const unsigned short* srcA = xb + (size_t)tm * 256 * K;
    const unsigned short* srcB = wb + (size_t)tn * 256 * K;

    const int rloc  = lane >> 3;
    const int sslot = (lane & 7) ^ rloc;

    f32x4 acc[4][4] = {};

    auto stage = [&](int buf, int kt) {
        const size_t coff = (size_t)kt * 64 + sslot * 8;
#pragma unroll
        for (int c = 0; c < 2; ++c) {
            const int row = c * 128 + wave * 8;
            gload_lds16(srcA + (size_t)(row + rloc) * K + coff,
                        &As[buf][row * 64]);
        }
#pragma unroll
        for (int c = 0; c < 2; ++c) {
            const int row = c * 128 + wave * 8;
            gload_lds16(srcB + (size_t)(row + rloc) * K + coff,
                        &Bs[buf][row * 64]);
        }
    };

    auto compute = [&](int buf) {
#pragma unroll
        for (int ks = 0; ks < 2; ++ks) {
            const int sl = s0 ^ (ks * 4);
            bf16x8 af[4], bg[4];
#pragma unroll
            for (int mf = 0; mf < 4; ++mf)
                af[mf] = *(const bf16x8*)
                    &As[buf][(wr * 64 + mf * 16 + frow) * 64 + sl * 8];
#pragma unroll
            for (int nf = 0; nf < 4; ++nf)
                bg[nf] = *(const bf16x8*)
                    &Bs[buf][(wc * 64 + nf * 16 + frow) * 64 + sl * 8];
            __builtin_amdgcn_s_setprio(1);
#pragma unroll
            for (int mf = 0; mf < 4; ++mf)
#pragma unroll
                for (int nf = 0; nf < 4; ++nf)
                    acc[mf][nf] = __builtin_amdgcn_mfma_f32_16x16x32_bf16(
                        af[mf], bg[nf], acc[mf][nf], 0, 0, 0);
            __builtin_amdgcn_s_setprio(0);
        }
    };

    stage(0, 0);
    stage(1, 1);

    for (int kt = 0; kt < NT - 2; ++kt) {
        asm volatile("s_waitcnt vmcnt(4)" ::: "memory");
        __builtin_amdgcn_s_barrier();
        compute(kt & 1);
        asm volatile("" ::: "memory");
        __builtin_amdgcn_s_barrier();
        stage(kt & 1, kt + 2);
    }
    asm volatile("s_waitcnt vmcnt(4)" ::: "memory");
    __builtin_amdgcn_s_barrier();
    compute((NT - 2) & 1);
    asm volatile("" ::: "memory");
    __builtin_amdgcn_s_barrier();
    asm volatile("s_waitcnt vmcnt(0)" ::: "memory");
    __builtin_amdgcn_s_barrier();
    compute((NT - 1) & 1);

    const int orow0 = tm * 256 + wr * 64 + klan * 4;
    const int ocol0 = tn * 256 + wc * 64 + frow;
#pragma unroll
    for (int mf = 0; mf < 4; ++mf)
#pragma unroll
        for (int nf = 0; nf < 4; ++nf)
#pragma unroll
            for (int r = 0; r < 4; ++r)
                out[(size_t)(orow0 + mf * 16 + r) * OUT_F + ocol0 + nf * 16]
                    = acc[mf][nf][r];
}

extern "C" void kernel_launch(void* const* d_in, const int* in_sizes, int n_in,
                              void* d_out, int out_size, void* d_ws, size_t ws_size,
                              hipStream_t stream) {
    const float*          x      = (const float*)d_in[0];
    const unsigned short* wbits  = (const unsigned short*)d_in[1];  // fp32-delivered
    const int*            coords = (const int*)d_in[2];             // int32
    float*                out    = (float*)d_out;                   // fp32

    const size_t MB = 1024 * 1024;
    float*          W  = out + W_BASE;                            // 16 MiB, dies pre-GEMM
    unsigned short* wb = (unsigned short*)d_ws;                   // 8 MiB
    unsigned short* xb = (unsigned short*)((char*)d_ws + 8 * MB); // 32 MiB (ws>=40 proven)
    (void)ws_size; (void)in_sizes; (void)n_in; (void)out_size;

    zero_f32_kernel<<<512, 256, 0, stream>>>((float4*)W, OUT_F * IN_F / 4);
    scatter_xcvt_kernel<<<6144, 256, 0, stream>>>(
        wbits, coords, W, (const float4*)x, (ushort4*)xb);
    f32_to_bf16_kernel<<<1024, 256, 0, stream>>>(
        (const float4*)W, (ushort4*)wb, OUT_F * IN_F / 4);

    gemm256_kernel<<<256, 1024, 0, stream>>>(xb, wb, out);
}

// Round 17
// 139.968 us; speedup vs baseline: 2.4663x; 1.0530x over previous
//
#include <hip/hip_runtime.h>
#include <hip/hip_fp16.h>

#define IN_F   2048
#define OUT_F  2048
#define NNZ_   1048576
#define BATCH  8192
#define W_ROW0 6144
#define W_BASE ((size_t)W_ROW0 * OUT_F)   // W fp32 parked at out rows [6144,8192)

typedef __bf16 bf16x8 __attribute__((ext_vector_type(8)));
typedef float  f32x4  __attribute__((ext_vector_type(4)));

__device__ __forceinline__ float bfval(unsigned short b) {
    union { unsigned int u; float f; } t; t.u = ((unsigned int)b) << 16; return t.f;
}
__device__ __forceinline__ unsigned short f2bf(float f) {
    union { float f; unsigned int u; } v; v.f = f;
    unsigned int u = v.u; u += 0x7FFF + ((u >> 16) & 1);   // RNE
    return (unsigned short)(u >> 16);
}
__device__ __forceinline__ float h2f(unsigned short b) {
    union { unsigned short u; __half h; } t; t.u = b; return __half2float(t.h);
}
__device__ __forceinline__ void gload_lds16(const void* g, void* l) {
    __builtin_amdgcn_global_load_lds(
        (const __attribute__((address_space(1))) unsigned int*)g,
        (__attribute__((address_space(3))) unsigned int*)l,
        16, 0, 0);
}

// ---- zero W region (must globally precede scatter atomics) ----
__global__ void zero_f32_kernel(float4* __restrict__ p, int n4) {
    int s = gridDim.x * blockDim.x;
    for (int i = blockIdx.x * blockDim.x + threadIdx.x; i < n4; i += s)
        p[i] = float4{0.f, 0.f, 0.f, 0.f};
}

// ---- fused: blocks [0,512) scatter (8-deep pipelined atomics);
//      blocks [512,2048) x->bf16. 2048 blocks = 32 waves/CU, one generation.
__global__ void scatter_xcvt_kernel(const unsigned short* __restrict__ wbits,
                                    const int* __restrict__ coords,
                                    float* __restrict__ W,
                                    const float4* __restrict__ x,
                                    ushort4* __restrict__ xb) {
    if (blockIdx.x < 512) {
        // ---- weights-dtype detector (r9-proven) ----
        __shared__ unsigned int sbf, sfh;
        if (threadIdx.x == 0) { sbf = 0u; sfh = 0u; }
        __syncthreads();
        unsigned int mbf = 0u, mfh = 0u;
        for (int i = threadIdx.x; i < 512; i += blockDim.x) {
            unsigned short b = wbits[i];
            unsigned int abf = (((unsigned int)b) << 16) & 0x7FFFFFFFu;
            unsigned int afh = (unsigned int)(b & 0x7FFF);
            mbf = mbf > abf ? mbf : abf;
            mfh = mfh > afh ? mfh : afh;
        }
        atomicMax(&sbf, mbf); atomicMax(&sfh, mfh);
        __syncthreads();
        union { unsigned int u; float f; } tb; tb.u = sbf;
        float bmax = tb.f;
        float hmax = h2f((unsigned short)sfh);
        int mode = (bmax > 1e-3f && bmax < 16.f) ? 0
                 : (hmax > 1e-3f && hmax < 16.f) ? 1 : 2;  // on HW: 2 (fp32)

        // 8 fire-and-forget atomics per thread, back-to-back (latency overlap)
        const int stride = 512 * 256;
#pragma unroll
        for (int it = 0; it < 8; ++it) {
            int i = it * stride + blockIdx.x * 256 + threadIdx.x;  // < NNZ_
            float v;
            if (mode == 0)      v = bfval(wbits[i]);
            else if (mode == 1) v = h2f(wbits[i]);
            else                v = ((const float*)wbits)[i];
            atomicAdd(&W[coords[i] & (OUT_F * IN_F - 1)], v);
        }
    } else {
        // ---- x fp32 -> xb bf16 over 1536 blocks ----
        const int t0     = (blockIdx.x - 512) * 256 + threadIdx.x;
        const int stride = 1536 * 256;
        for (int i = t0; i < BATCH * IN_F / 4; i += stride) {
            float4 v = x[i];
            ushort4 o;
            o.x = f2bf(v.x); o.y = f2bf(v.y); o.z = f2bf(v.z); o.w = f2bf(v.w);
            xb[i] = o;
        }
    }
}

// ---- W fp32 -> wb bf16 ----
__global__ void f32_to_bf16_kernel(const float4* __restrict__ in,
                                   ushort4* __restrict__ out, int n4) {
    int s = gridDim.x * blockDim.x;
    for (int i = blockIdx.x * blockDim.x + threadIdx.x; i < n4; i += s) {
        float4 v = in[i];
        ushort4 o;
        o.x = f2bf(v.x); o.y = f2bf(v.y); o.z = f2bf(v.z); o.w = f2bf(v.w);
        out[i] = o;
    }
}

// ---- 256x256 bf16 GEMM (r14 VERBATIM) ----
__global__ __launch_bounds__(1024, 4) void gemm256_kernel(
    const unsigned short* __restrict__ xb,
    const unsigned short* __restrict__ wb,
    float* __restrict__ out) {
    constexpr int K = IN_F;
    constexpr int NT = K / 64;                 // 32 K-tiles

    __shared__ __align__(16) unsigned short As[2][256 * 64];   // 64 KiB
    __shared__ __align__(16) unsigned short Bs[2][256 * 64];   // 64 KiB

    const int tid  = threadIdx.x;
    const int lane = tid & 63;
    const int wave = tid >> 6;        // 0..15
    const int wr   = wave >> 2;       // M quarter
    const int wc   = wave & 3;        // N quarter
    const int frow = lane & 15;
    const int klan = lane >> 4;
    const int s0   = klan ^ (lane & 7);

    const int flat = blockIdx.x;
    const int swz  = (flat & 7) * 32 + (flat >> 3);   // XCD swizzle
    const int tm   = swz & 31;
    const int tn   = swz >> 5;

    const unsigned short* srcA = xb + (size_t)tm * 256 * K;
    const unsigned short* srcB = wb + (size_t)tn * 256 * K;

    const int rloc  = lane >> 3;
    const int sslot = (lane & 7) ^ rloc;

    f32x4 acc[4][4] = {};

    auto stage = [&](int buf, int kt) {
        const size_t coff = (size_t)kt * 64 + sslot * 8;
#pragma unroll
        for (int c = 0; c < 2; ++c) {
            const int row = c * 128 + wave * 8;
            gload_lds16(srcA + (size_t)(row + rloc) * K + coff,
                        &As[buf][row * 64]);
        }
#pragma unroll
        for (int c = 0; c < 2; ++c) {
            const int row = c * 128 + wave * 8;
            gload_lds16(srcB + (size_t)(row + rloc) * K + coff,
                        &Bs[buf][row * 64]);
        }
    };

    auto compute = [&](int buf) {
#pragma unroll
        for (int ks = 0; ks < 2; ++ks) {
            const int sl = s0 ^ (ks * 4);
            bf16x8 af[4], bg[4];
#pragma unroll
            for (int mf = 0; mf < 4; ++mf)
                af[mf] = *(const bf16x8*)
                    &As[buf][(wr * 64 + mf * 16 + frow) * 64 + sl * 8];
#pragma unroll
            for (int nf = 0; nf < 4; ++nf)
                bg[nf] = *(const bf16x8*)
                    &Bs[buf][(wc * 64 + nf * 16 + frow) * 64 + sl * 8];
            __builtin_amdgcn_s_setprio(1);
#pragma unroll
            for (int mf = 0; mf < 4; ++mf)
#pragma unroll
                for (int nf = 0; nf < 4; ++nf)
                    acc[mf][nf] = __builtin_amdgcn_mfma_f32_16x16x32_bf16(
                        af[mf], bg[nf], acc[mf][nf], 0, 0, 0);
            __builtin_amdgcn_s_setprio(0);
        }
    };

    stage(0, 0);
    stage(1, 1);

    for (int kt = 0; kt < NT - 2; ++kt) {
        asm volatile("s_waitcnt vmcnt(4)" ::: "memory");
        __builtin_amdgcn_s_barrier();
        compute(kt & 1);
        asm volatile("" ::: "memory");
        __builtin_amdgcn_s_barrier();
        stage(kt & 1, kt + 2);
    }
    asm volatile("s_waitcnt vmcnt(4)" ::: "memory");
    __builtin_amdgcn_s_barrier();
    compute((NT - 2) & 1);
    asm volatile("" ::: "memory");
    __builtin_amdgcn_s_barrier();
    asm volatile("s_waitcnt vmcnt(0)" ::: "memory");
    __builtin_amdgcn_s_barrier();
    compute((NT - 1) & 1);

    const int orow0 = tm * 256 + wr * 64 + klan * 4;
    const int ocol0 = tn * 256 + wc * 64 + frow;
#pragma unroll
    for (int mf = 0; mf < 4; ++mf)
#pragma unroll
        for (int nf = 0; nf < 4; ++nf)
#pragma unroll
            for (int r = 0; r < 4; ++r)
                out[(size_t)(orow0 + mf * 16 + r) * OUT_F + ocol0 + nf * 16]
                    = acc[mf][nf][r];
}

extern "C" void kernel_launch(void* const* d_in, const int* in_sizes, int n_in,
                              void* d_out, int out_size, void* d_ws, size_t ws_size,
                              hipStream_t stream) {
    const float*          x      = (const float*)d_in[0];
    const unsigned short* wbits  = (const unsigned short*)d_in[1];  // fp32-delivered
    const int*            coords = (const int*)d_in[2];             // int32
    float*                out    = (float*)d_out;                   // fp32

    const size_t MB = 1024 * 1024;
    float*          W  = out + W_BASE;                            // 16 MiB, dies pre-GEMM
    unsigned short* wb = (unsigned short*)d_ws;                   // 8 MiB
    unsigned short* xb = (unsigned short*)((char*)d_ws + 8 * MB); // 32 MiB (ws>=40 proven)
    (void)ws_size; (void)in_sizes; (void)n_in; (void)out_size;

    zero_f32_kernel<<<512, 256, 0, stream>>>((float4*)W, OUT_F * IN_F / 4);
    scatter_xcvt_kernel<<<2048, 256, 0, stream>>>(
        wbits, coords, W, (const float4*)x, (ushort4*)xb);
    f32_to_bf16_kernel<<<1024, 256, 0, stream>>>(
        (const float4*)W, (ushort4*)wb, OUT_F * IN_F / 4);

    gemm256_kernel<<<256, 1024, 0, stream>>>(xb, wb, out);
}